// Round 1
// baseline (24.141 us; speedup 1.0000x reference)
//
#include <hip/hip_runtime.h>

#define B_N 4096
#define K_N 50
#define D_N 128
#define WAVES_PER_BLOCK 4
#define BLOCK_T 256
#define NBLOCKS (B_N / WAVES_PER_BLOCK)   // 1024

__global__ __launch_bounds__(BLOCK_T) void disloss_main(
    const float* __restrict__ emb_batch,   // [B, D]
    const float* __restrict__ embedding,   // [V, D]
    const float* __restrict__ attr_sim,    // [B, K]
    const int*   __restrict__ indices,     // [B, K]
    float*       __restrict__ partials)    // [NBLOCKS]
{
    const int wave = threadIdx.x >> 6;     // 0..3
    const int lane = threadIdx.x & 63;     // 0..63
    const int b = blockIdx.x * WAVES_PER_BLOCK + wave;

    // This sample's embedding slice: 2 consecutive floats per lane (512 B/wave, coalesced)
    const float2 eb = *reinterpret_cast<const float2*>(&emb_batch[(size_t)b * D_N + lane * 2]);

    // Preload this sample's K indices + attr weights into lanes 0..K-1
    int   myidx  = 0;
    float myattr = 0.0f;
    if (lane < K_N) {
        myidx  = indices[(size_t)b * K_N + lane];
        myattr = attr_sim[(size_t)b * K_N + lane];
    }

    float acc = 0.0f;
    #pragma unroll 10
    for (int k = 0; k < K_N; ++k) {
        const int   idx = __shfl(myidx,  k);
        const float a   = __shfl(myattr, k);
        const float2 g = *reinterpret_cast<const float2*>(
            &embedding[(size_t)idx * D_N + lane * 2]);
        const float dx = g.x - eb.x;
        const float dy = g.y - eb.y;
        acc += a * (dx * dx + dy * dy);
    }

    // Wave reduction (64 lanes)
    #pragma unroll
    for (int off = 32; off > 0; off >>= 1)
        acc += __shfl_down(acc, off);

    __shared__ float s[WAVES_PER_BLOCK];
    if (lane == 0) s[wave] = acc;
    __syncthreads();
    if (threadIdx.x == 0)
        partials[blockIdx.x] = s[0] + s[1] + s[2] + s[3];
}

__global__ __launch_bounds__(BLOCK_T) void disloss_reduce(
    const float* __restrict__ partials,
    float*       __restrict__ out)
{
    float acc = 0.0f;
    for (int i = threadIdx.x; i < NBLOCKS; i += BLOCK_T)
        acc += partials[i];

    #pragma unroll
    for (int off = 32; off > 0; off >>= 1)
        acc += __shfl_down(acc, off);

    __shared__ float s[WAVES_PER_BLOCK];
    const int wave = threadIdx.x >> 6;
    const int lane = threadIdx.x & 63;
    if (lane == 0) s[wave] = acc;
    __syncthreads();
    if (threadIdx.x == 0)
        out[0] = (s[0] + s[1] + s[2] + s[3]) / (float)B_N;
}

extern "C" void kernel_launch(void* const* d_in, const int* in_sizes, int n_in,
                              void* d_out, int out_size, void* d_ws, size_t ws_size,
                              hipStream_t stream) {
    const float* emb_batch = (const float*)d_in[0];   // [B, D]
    const float* embedding = (const float*)d_in[1];   // [V, D]
    const float* attr_sim  = (const float*)d_in[2];   // [B, K]
    const int*   indices   = (const int*)d_in[3];     // [B, K]
    // d_in[4] = beta (unused by the reference computation)

    float* out      = (float*)d_out;
    float* partials = (float*)d_ws;                   // NBLOCKS floats (4 KB)

    disloss_main<<<NBLOCKS, BLOCK_T, 0, stream>>>(emb_batch, embedding, attr_sim,
                                                  indices, partials);
    disloss_reduce<<<1, BLOCK_T, 0, stream>>>(partials, out);
}